// Round 1
// 414.570 us; speedup vs baseline: 1.0319x; 1.0319x over previous
//
#include <hip/hip_runtime.h>
#include <math.h>

#define BATCH 2048
#define N_TIME 2048
#define INPUT_SIZE 28
#define OUTPUT_SIZE 7
#define N_S 4
#define PERIOD 7
#define EMBED 9
#define SEAS_LEN (N_TIME + PERIOD)       // 2055
#define W_COUNT 288                      // len(range(0, 2014, 7))
#define WB_COUNT (W_COUNT * BATCH)       // 589824
#define INS_COLS 67                      // 28 + 35 + 4
#define OUT0_SIZE (WB_COUNT * INS_COLS)  // 39,518,208 (multiple of 256)
#define OUT1_SIZE (WB_COUNT * OUTPUT_SIZE) // 4,128,768 (multiple of 256)
#define LEV_SIZE (BATCH * N_TIME)
#define SEAS_SIZE (BATCH * SEAS_LEN)

// ---------------------------------------------------------------------------
// Phase 1 scan, software-pipelined.
// Key identity: s_k = ns_{k-7} is known 7 steps early, so we keep
//   sbuf[i] = s_{g+i}         (seasonal values for the next 7 steps)
//   rbuf[i] = lev_sms*rcp(s_{g+i})   (filled 5 steps before use)
// and the level recurrence becomes ONE fma on the carried value:
//   nl = fma(oma, lev, y * rbuf[0])
// The seasonal finish for step g-1 runs at step g using rnl_{g-1} = rcp(nl_{g-1})
// issued one step earlier (rcp latency hidden); its rcp(ns) is scaled one
// further step later (needed only 5 steps ahead). Tile column map:
//   tl col j  <-> levels   col base+j      (col 0 = carry-in level)
//   ts col j  <-> seasonal col base+7+j    (= ns_{base+j-1}; one step late)
// Single wave per block -> __syncthreads replaced by lgkmcnt-only fences
// (no vmcnt(0) drain of the ~80 in-flight global stores per chunk).
// ---------------------------------------------------------------------------
struct ScanState {
    float lev, lsms, seas_sms, oma, oms;
    float sbuf[PERIOD];   // s_{g}..s_{g+6} at entry to step g (slot 6 refreshed in-step)
    float rbuf[PERIOD];   // lsms * rcp(s_{g+i})
    float yp, sp, rnlp, rnsp;  // pipeline: y_{g-1}, s_{g-1}, rcp(nl_{g-1}), rcp(ns_{g-2})
};

template<bool FIRST, bool LAST, bool PREF>
__device__ __forceinline__ void scan_chunk(
    int base, int l, int r0, int jr, int km,
    const float* __restrict__ Yb,
    float (&cur)[64], float (&nxt)[64],
    float (*__restrict__ tl)[65], float (*__restrict__ ts)[65],
    ScanState& st,
    float* __restrict__ levels, float* __restrict__ seasonal)
{
    if (PREF) {
#pragma unroll
        for (int k = 0; k < 64; k += 4)
            *(float4*)&nxt[k] = *(const float4*)(Yb + base + 64 + k);
    }
    tl[l][0] = st.lev;                 // carry-in: levels col `base`
#pragma unroll
    for (int k = 0; k < 64; ++k) {
        if (!LAST || k < 63) {         // last chunk has 63 steps
            float y  = (k < 63) ? cur[k + 1] : nxt[0];
            float s0 = st.sbuf[0];
            // --- level: single dependent fma (all other operands steps-old)
            float nl = fmaf(st.oma, st.lev, y * st.rbuf[0]);
            st.lev = nl;
            tl[l][k + 1] = nl;
            // --- finish PREVIOUS step's seasonal (rcp latency hidden)
            if (!FIRST || k > 0) {
                float u  = st.yp * st.rnlp;
                float ns = fmaf(st.oms, st.sp, st.seas_sms * u);
                ts[l][k] = ns;                 // seasonal col base+7+k = ns_{g-1}
                st.sbuf[PERIOD - 1] = ns;      // s_{g+6}
                // scale the 2-steps-old rcp(ns) into rbuf (entry for s_{g+5})
                if (!FIRST || k > 1)
                    st.rbuf[PERIOD - 2] = st.lsms * st.rnsp;
                st.rnsp = __builtin_amdgcn_rcpf(ns);
            }
            float rnl = __builtin_amdgcn_rcpf(nl);   // consumed next step
            // --- shift (pure register renaming after full unroll)
#pragma unroll
            for (int q = 0; q < PERIOD - 1; ++q) st.sbuf[q] = st.sbuf[q + 1];
#pragma unroll
            for (int q = 0; q < PERIOD - 1; ++q) st.rbuf[q] = st.rbuf[q + 1];
            st.yp = y; st.sp = s0; st.rnlp = rnl;
        }
    }
    if (LAST) {                        // drain the pipeline: ns_{2046}
        float u  = st.yp * st.rnlp;
        float ns = fmaf(st.oms, st.sp, st.seas_sms * u);
        ts[l][63] = ns;                // seasonal col 2054
    }
    // single wave: LDS ordering only, no vmcnt drain / no s_barrier needed
    asm volatile("s_waitcnt lgkmcnt(0)" ::: "memory");
#pragma unroll
    for (int j0 = 0; j0 < 64; j0 += 4) {
        int j = j0 + jr;               // tile row = local batch row
        float vl[4], vs[4];
#pragma unroll
        for (int i = 0; i < 4; ++i) { vl[i] = tl[j][km + i]; vs[i] = ts[j][km + i]; }
        float4 v4; v4.x = vl[0]; v4.y = vl[1]; v4.z = vl[2]; v4.w = vl[3];
        *(float4*)(levels + (size_t)(r0 + j) * N_TIME + base + km) = v4;
        float* srow = seasonal + (size_t)(r0 + j) * SEAS_LEN + base + 7 + km;
#pragma unroll
        for (int i = 0; i < 4; ++i) srow[i] = vs[i];
    }
    asm volatile("s_waitcnt lgkmcnt(0)" ::: "memory");
}

__global__ __launch_bounds__(64) void es_scan(
    const float* __restrict__ Y, const int* __restrict__ idxs,
    const float* __restrict__ emb,
    float* __restrict__ levels, float* __restrict__ seasonal)
{
    __shared__ float tl[64][65];
    __shared__ float ts[64][65];
    const int l  = threadIdx.x;
    const int r0 = blockIdx.x * 64;
    const int b  = r0 + l;
    const float* Yb = Y + (size_t)b * N_TIME;
    const int jr = l >> 4;
    const int km = (l & 15) * 4;

    const float* e = emb + (size_t)idxs[b] * EMBED;
    ScanState st;
    st.lsms     = 1.0f / (1.0f + __expf(-e[0]));
    st.seas_sms = 1.0f / (1.0f + __expf(-e[1]));
    st.oma = 1.0f - st.lsms;
    st.oms = 1.0f - st.seas_sms;
    float is[PERIOD];
#pragma unroll
    for (int j = 0; j < PERIOD; ++j) is[j] = __expf(e[2 + j]);
    st.lev = Yb[0] / is[0];

    float* seab = seasonal + (size_t)b * SEAS_LEN;
#pragma unroll
    for (int j = 0; j < PERIOD; ++j) seab[j] = is[j];
    ts[l][0] = is[0];                  // seasonal col 7 (= "ns_{-1}") for chunk 0
#pragma unroll
    for (int j = 0; j < PERIOD; ++j) st.sbuf[j] = is[(j + 1) % PERIOD];
#pragma unroll
    for (int j = 0; j < PERIOD; ++j)
        st.rbuf[j] = st.lsms * __builtin_amdgcn_rcpf(st.sbuf[j]);
    st.yp = 0.0f; st.sp = 1.0f; st.rnlp = 1.0f; st.rnsp = 1.0f; // set before use

    float ya[64], yb2[64];
#pragma unroll
    for (int k = 0; k < 64; k += 4)
        *(float4*)&ya[k] = *(const float4*)(Yb + k);

    // chunk 0 (FIRST: pipeline warm-up guards), then pairs, then LAST (63 steps)
    scan_chunk<true,  false, true >(0, l, r0, jr, km, Yb, ya, yb2, tl, ts, st, levels, seasonal);
#pragma unroll 1
    for (int cc = 0; cc < 15; ++cc) {
        scan_chunk<false, false, true>(64  + cc * 128, l, r0, jr, km, Yb, yb2, ya, tl, ts, st, levels, seasonal);
        scan_chunk<false, false, true>(128 + cc * 128, l, r0, jr, km, Yb, ya, yb2, tl, ts, st, levels, seasonal);
    }
    scan_chunk<false, true,  false>(1984, l, r0, jr, km, Yb, yb2, ya, tl, ts, st, levels, seasonal);
}

// ---------------------------------------------------------------------------
// Phase 2: window materialization (unchanged this round). gid is a LINEAR
// index into out0 (then out1) -> every store consecutive, full 64B lines.
// ---------------------------------------------------------------------------
__global__ __launch_bounds__(256) void es_windows(
    const float* __restrict__ Y, const float* __restrict__ X,
    const float* __restrict__ S, const float* __restrict__ levels,
    const float* __restrict__ seasonal,
    float* __restrict__ out0, float* __restrict__ out1)
{
    int gid = blockIdx.x * 256 + threadIdx.x;
    if (gid < OUT0_SIZE) {
        unsigned u  = (unsigned)gid;
        unsigned wb = u / 67u;
        int j  = (int)(u - wb * 67u);
        int w  = (int)(wb >> 11);
        int b  = (int)(wb & (BATCH - 1));
        int t0 = w * 7;
        float v;
        if (j < INPUT_SIZE) {
            float y  = Y[b * N_TIME + t0 + j];
            float lv = levels[b * N_TIME + t0 + INPUT_SIZE - 1];
            float sv = seasonal[b * SEAS_LEN + t0 + j];
            v = __logf(y * __builtin_amdgcn_rcpf(lv * sv));
        } else if (j < 63) {
            v = X[b * N_TIME + t0 + (j - INPUT_SIZE)];
        } else {
            v = S[b * N_S + (j - 63)];
        }
        out0[gid] = v;
    } else {
        unsigned e  = (unsigned)(gid - OUT0_SIZE);
        unsigned wb = e / 7u;
        int m  = (int)(e - wb * 7u);
        int w  = (int)(wb >> 11);
        int b  = (int)(wb & (BATCH - 1));
        out1[e] = Y[b * N_TIME + w * 7 + INPUT_SIZE + m];
    }
}

extern "C" void kernel_launch(void* const* d_in, const int* in_sizes, int n_in,
                              void* d_out, int out_size, void* d_ws, size_t ws_size,
                              hipStream_t stream) {
    const float* S    = (const float*)d_in[0];
    const float* Y    = (const float*)d_in[1];
    const float* X    = (const float*)d_in[2];
    const int*   idxs = (const int*)d_in[3];
    const float* emb  = (const float*)d_in[4];

    float* out      = (float*)d_out;
    float* out_ins  = out;                                    // (W,B,67)
    float* out_outs = out + OUT0_SIZE;                        // (W,B,7)
    float* levels   = out + OUT0_SIZE + OUT1_SIZE;            // (B,2048)
    float* seasonal = out + OUT0_SIZE + OUT1_SIZE + LEV_SIZE; // (B,2055)

    es_scan<<<BATCH / 64, 64, 0, stream>>>(Y, idxs, emb, levels, seasonal);

    const int total = OUT0_SIZE + OUT1_SIZE;                  // 43,646,976
    es_windows<<<total / 256, 256, 0, stream>>>(
        Y, X, S, levels, seasonal, out_ins, out_outs);
}

// Round 2
// 356.472 us; speedup vs baseline: 1.2001x; 1.1630x over previous
//
#include <hip/hip_runtime.h>
#include <math.h>

#define BATCH 2048
#define N_TIME 2048
#define INPUT_SIZE 28
#define OUTPUT_SIZE 7
#define N_S 4
#define PERIOD 7
#define EMBED 9
#define SEAS_LEN (N_TIME + PERIOD)       // 2055
#define W_COUNT 288                      // len(range(0, 2014, 7))
#define WB_COUNT (W_COUNT * BATCH)       // 589824
#define INS_COLS 67                      // 28 + 35 + 4
#define OUT0_SIZE (WB_COUNT * INS_COLS)  // 39,518,208 (multiple of 256)
#define OUT1_SIZE (WB_COUNT * OUTPUT_SIZE) // 4,128,768 (multiple of 256)
#define LEV_SIZE (BATCH * N_TIME)
#define SEAS_SIZE (BATCH * SEAS_LEN)

// ---------------------------------------------------------------------------
// Phase 1 scan: producer-consumer wave split, 32 blocks x 128 threads.
//   wave 0 (producer): software-pipelined recurrence only. Per step: 1 fma on
//     the carried level (s_k = ns_{k-7} known 7 steps early -> rbuf), deferred
//     seasonal finish, 2 ds_writes into the current tile buffer.
//   wave 1 (consumer): drains the finished tile (transpose via LDS, coalesced
//     global stores) CONCURRENTLY with the producer's next chunk.
// Double-buffered tiles (66.5 KB LDS, 1 block/CU). Sync = one raw s_barrier
// per chunk + lgkmcnt(0)-only fences (no vmcnt drain anywhere).
// Race check: producer rewrites buffer p at chunk c+2 only after barrier c+1,
// which the consumer joins only after its reads of buffer p completed.
// Tile map: tl col j <-> levels col base+j (col 0 = carry-in);
//           ts col j <-> seasonal col base+7+j (pipelined finish is 1 late;
//           LAST chunk drains the pipeline into ts col 63 before the barrier,
//           so the consumer stores all 64 cols unconditionally).
// ---------------------------------------------------------------------------
struct ScanState {
    float lev, lsms, seas_sms, oma, oms;
    float sbuf[PERIOD];   // s_{g}..s_{g+6} at entry to step g
    float rbuf[PERIOD];   // lsms * rcp(s_{g+i})
    float yp, sp, rnlp, rnsp;  // pipeline: y_{g-1}, s_{g-1}, rcp(nl_{g-1}), rcp(ns_{g-2})
};

template<bool FIRST, bool LAST, bool PREF>
__device__ __forceinline__ void scan_chunk(
    int base, int l,
    const float* __restrict__ Yb,
    float (&cur)[64], float (&nxt)[64],
    float (*__restrict__ tl)[65], float (*__restrict__ ts)[65],
    ScanState& st)
{
    if (PREF) {
#pragma unroll
        for (int k = 0; k < 64; k += 4)
            *(float4*)&nxt[k] = *(const float4*)(Yb + base + 64 + k);
    }
    tl[l][0] = st.lev;                 // carry-in: levels col `base`
#pragma unroll
    for (int k = 0; k < 64; ++k) {
        if (!LAST || k < 63) {         // last chunk has 63 steps
            float y  = (k < 63) ? cur[k + 1] : nxt[0];
            float s0 = st.sbuf[0];
            // --- level: single dependent fma (all other operands steps-old)
            float nl = fmaf(st.oma, st.lev, y * st.rbuf[0]);
            st.lev = nl;
            tl[l][k + 1] = nl;
            // --- finish PREVIOUS step's seasonal (rcp latency hidden)
            if (!FIRST || k > 0) {
                float u  = st.yp * st.rnlp;
                float ns = fmaf(st.oms, st.sp, st.seas_sms * u);
                ts[l][k] = ns;                 // seasonal col base+7+k = ns_{g-1}
                st.sbuf[PERIOD - 1] = ns;      // s_{g+6}
                if (!FIRST || k > 1)
                    st.rbuf[PERIOD - 2] = st.lsms * st.rnsp;
                st.rnsp = __builtin_amdgcn_rcpf(ns);
            }
            float rnl = __builtin_amdgcn_rcpf(nl);   // consumed next step
#pragma unroll
            for (int q = 0; q < PERIOD - 1; ++q) st.sbuf[q] = st.sbuf[q + 1];
#pragma unroll
            for (int q = 0; q < PERIOD - 1; ++q) st.rbuf[q] = st.rbuf[q + 1];
            st.yp = y; st.sp = s0; st.rnlp = rnl;
        }
    }
    if (LAST) {                        // drain the pipeline: ns_{2046}
        float u  = st.yp * st.rnlp;
        float ns = fmaf(st.oms, st.sp, st.seas_sms * u);
        ts[l][63] = ns;                // seasonal col 2054
    }
    // make tile writes visible, then hand off to the consumer wave
    asm volatile("s_waitcnt lgkmcnt(0)" ::: "memory");
    __builtin_amdgcn_s_barrier();
}

__device__ __forceinline__ void drain_chunk(
    int base, int jr, int km, int r0,
    const float (*__restrict__ tl)[65], const float (*__restrict__ ts)[65],
    float* __restrict__ levels, float* __restrict__ seasonal)
{
    __builtin_amdgcn_s_barrier();      // wait for producer to finish this tile
    asm volatile("" ::: "memory");     // no hoisting of reads above the barrier
#pragma unroll
    for (int j0 = 0; j0 < 64; j0 += 4) {
        int j = j0 + jr;               // tile row = local batch row
        float vl[4], vs[4];
#pragma unroll
        for (int i = 0; i < 4; ++i) { vl[i] = tl[j][km + i]; vs[i] = ts[j][km + i]; }
        float4 v4; v4.x = vl[0]; v4.y = vl[1]; v4.z = vl[2]; v4.w = vl[3];
        *(float4*)(levels + (size_t)(r0 + j) * N_TIME + base + km) = v4;
        float* srow = seasonal + (size_t)(r0 + j) * SEAS_LEN + base + 7 + km;
#pragma unroll
        for (int i = 0; i < 4; ++i) srow[i] = vs[i];
    }
    // reads must be complete before joining the next barrier (buffer reuse)
    asm volatile("s_waitcnt lgkmcnt(0)" ::: "memory");
}

__global__ __launch_bounds__(128) void es_scan(
    const float* __restrict__ Y, const int* __restrict__ idxs,
    const float* __restrict__ emb,
    float* __restrict__ levels, float* __restrict__ seasonal)
{
    __shared__ float tl[2][64][65];
    __shared__ float ts[2][64][65];
    const int tid = threadIdx.x;
    const int l   = tid & 63;
    const int r0  = blockIdx.x * 64;

    if (tid < 64) {
        // ---------------- producer wave: the recurrence ----------------
        const int b = r0 + l;
        const float* Yb = Y + (size_t)b * N_TIME;
        const float* e  = emb + (size_t)idxs[b] * EMBED;
        ScanState st;
        st.lsms     = 1.0f / (1.0f + __expf(-e[0]));
        st.seas_sms = 1.0f / (1.0f + __expf(-e[1]));
        st.oma = 1.0f - st.lsms;
        st.oms = 1.0f - st.seas_sms;
        float is[PERIOD];
#pragma unroll
        for (int j = 0; j < PERIOD; ++j) is[j] = __expf(e[2 + j]);
        st.lev = Yb[0] / is[0];

        float* seab = seasonal + (size_t)b * SEAS_LEN;
#pragma unroll
        for (int j = 0; j < PERIOD; ++j) seab[j] = is[j];
        ts[0][l][0] = is[0];           // seasonal col 7 (= "ns_{-1}") for chunk 0
#pragma unroll
        for (int j = 0; j < PERIOD; ++j) st.sbuf[j] = is[(j + 1) % PERIOD];
#pragma unroll
        for (int j = 0; j < PERIOD; ++j)
            st.rbuf[j] = st.lsms * __builtin_amdgcn_rcpf(st.sbuf[j]);
        st.yp = 0.0f; st.sp = 1.0f; st.rnlp = 1.0f; st.rnsp = 1.0f;

        float ya[64], yb2[64];
#pragma unroll
        for (int k = 0; k < 64; k += 4)
            *(float4*)&ya[k] = *(const float4*)(Yb + k);

        // chunk 0 (FIRST), then pairs ping-ponging y-buffers, then LAST (63 steps)
        scan_chunk<true,  false, true >(0, l, Yb, ya, yb2, tl[0], ts[0], st);
#pragma unroll 1
        for (int cc = 0; cc < 15; ++cc) {
            scan_chunk<false, false, true>(64  + cc * 128, l, Yb, yb2, ya, tl[1], ts[1], st);
            scan_chunk<false, false, true>(128 + cc * 128, l, Yb, ya, yb2, tl[0], ts[0], st);
        }
        scan_chunk<false, true,  false>(1984, l, Yb, yb2, ya, tl[1], ts[1], st);
    } else {
        // ---------------- consumer wave: transpose + coalesced stores ----------------
        const int jr = l >> 4;
        const int km = (l & 15) * 4;
#pragma unroll 1
        for (int c = 0; c < 32; ++c)
            drain_chunk(c * 64, jr, km, r0, tl[c & 1], ts[c & 1], levels, seasonal);
    }
}

// ---------------------------------------------------------------------------
// Phase 2: window materialization (unchanged). gid is a LINEAR index into
// out0 (then out1) -> every store consecutive, full 64B lines.
// ---------------------------------------------------------------------------
__global__ __launch_bounds__(256) void es_windows(
    const float* __restrict__ Y, const float* __restrict__ X,
    const float* __restrict__ S, const float* __restrict__ levels,
    const float* __restrict__ seasonal,
    float* __restrict__ out0, float* __restrict__ out1)
{
    int gid = blockIdx.x * 256 + threadIdx.x;
    if (gid < OUT0_SIZE) {
        unsigned u  = (unsigned)gid;
        unsigned wb = u / 67u;
        int j  = (int)(u - wb * 67u);
        int w  = (int)(wb >> 11);
        int b  = (int)(wb & (BATCH - 1));
        int t0 = w * 7;
        float v;
        if (j < INPUT_SIZE) {
            float y  = Y[b * N_TIME + t0 + j];
            float lv = levels[b * N_TIME + t0 + INPUT_SIZE - 1];
            float sv = seasonal[b * SEAS_LEN + t0 + j];
            v = __logf(y * __builtin_amdgcn_rcpf(lv * sv));
        } else if (j < 63) {
            v = X[b * N_TIME + t0 + (j - INPUT_SIZE)];
        } else {
            v = S[b * N_S + (j - 63)];
        }
        out0[gid] = v;
    } else {
        unsigned e  = (unsigned)(gid - OUT0_SIZE);
        unsigned wb = e / 7u;
        int m  = (int)(e - wb * 7u);
        int w  = (int)(wb >> 11);
        int b  = (int)(wb & (BATCH - 1));
        out1[e] = Y[b * N_TIME + w * 7 + INPUT_SIZE + m];
    }
}

extern "C" void kernel_launch(void* const* d_in, const int* in_sizes, int n_in,
                              void* d_out, int out_size, void* d_ws, size_t ws_size,
                              hipStream_t stream) {
    const float* S    = (const float*)d_in[0];
    const float* Y    = (const float*)d_in[1];
    const float* X    = (const float*)d_in[2];
    const int*   idxs = (const int*)d_in[3];
    const float* emb  = (const float*)d_in[4];

    float* out      = (float*)d_out;
    float* out_ins  = out;                                    // (W,B,67)
    float* out_outs = out + OUT0_SIZE;                        // (W,B,7)
    float* levels   = out + OUT0_SIZE + OUT1_SIZE;            // (B,2048)
    float* seasonal = out + OUT0_SIZE + OUT1_SIZE + LEV_SIZE; // (B,2055)

    es_scan<<<BATCH / 64, 128, 0, stream>>>(Y, idxs, emb, levels, seasonal);

    const int total = OUT0_SIZE + OUT1_SIZE;                  // 43,646,976
    es_windows<<<total / 256, 256, 0, stream>>>(
        Y, X, S, levels, seasonal, out_ins, out_outs);
}